// Round 14
// baseline (32.534 us; speedup 1.0000x reference)
//
#include <hip/hip_runtime.h>
#include <hip/hip_bf16.h>
#include <math.h>

// Problem constants (from reference)
#define V_SZ 500000
#define E_SZ 128
#define H_SZ 128
#define L_SZ 10
#define P_SZ 10
#define N_SZ 50
#define NSEQ (P_SZ + N_SZ)       // 60 non-phrase sequences
#define NBLK 60                  // block j handles (seq 0, seq j+1)
#define TPB  512                 // 8 waves; wave w owns UNITS [16w,16w+16) for all 3 gates

#define FLAG_STRIDE 16
#define SLOT_STRIDE 16
#define FLAG_MAGIC  0x9E370000u

#define XS_STR  136              // xs_bf16 row stride (bf16): 272B, 16B-aligned
#define GI_USTR 132              // gi_all unit-dim stride (floats): 528B, 16B-aligned

typedef __attribute__((ext_vector_type(8))) short bf16x8;  // 8 bf16 = 4 VGPRs (MFMA A/B frag)
typedef __attribute__((ext_vector_type(4))) float f32x4;   // MFMA C/D frag

#define MFMA(a, b, c) __builtin_amdgcn_mfma_f32_16x16x32_bf16((a), (b), (c), 0, 0, 0)

__device__ __forceinline__ float sigmoidf(float x) {
    return 1.0f / (1.0f + expf(-x));
}

__device__ __forceinline__ unsigned short f2bf(float f) {   // RNE f32 -> bf16
    unsigned u = __float_as_uint(f);
    u += 0x7FFFu + ((u >> 16) & 1u);
    return (unsigned short)(u >> 16);
}

// Block j processes TWO sequences (col parity 0 = seq 0, parity 1 = seq j+1).
// Gate-ownership partition: wave w owns units [16w,16w+16) for r,z,n
// (A m-blocks w, w+8, w+16), so after the step MFMAs the gh values for a
// unit's three gates sit in ONE lane's registers -> in-register nonlinearity,
// no gh exchange, 1 barrier/step. Weights stage through one 96 KB LDS slab
// (2 passes), which is time-union'd with gi_all.
__global__ __launch_bounds__(TPB) void gru_fused(
    const int*   __restrict__ phr_inds,
    const int*   __restrict__ pos_inds,
    const int*   __restrict__ neg_inds,
    const float* __restrict__ u_emb,
    const float* __restrict__ v_emb,
    const float* __restrict__ w_ih,
    const float* __restrict__ w_hh,
    const float* __restrict__ b_ih,
    const float* __restrict__ b_hh,
    const float* __restrict__ h0,
    float*       __restrict__ slots,    // [NBLK*SLOT_STRIDE] workspace (s scalars)
    unsigned*    __restrict__ flags,    // [NBLK*FLAG_STRIDE] workspace
    float*       __restrict__ out)      // f32 scalar
{
    // 96 KB: full weight matrix (384 rows x 128 bf16, XOR-swizzled) during
    // staging; re-used as gi_all (31.7 KB f32) afterwards.
    __shared__ __align__(16) unsigned short stage_u[384 * E_SZ];      // 96 KB
    __shared__ __align__(16) unsigned short xs_bf16[2][16 * XS_STR];  // x^T per seq-group
    __shared__ __align__(16) unsigned short hs_bf16[2][2][H_SZ];      // [buf][seq][unit]
    __shared__ __align__(16) float          node[2][H_SZ];            // final h (f32)

    float* gi_all = (float*)stage_u;    // alias; valid after staging completes
    // gi_all flat layout: ((seq*L_SZ + l)*3 + gate)*GI_USTR + unit  (bias folded in)

    const int bj   = blockIdx.x;             // 0..59
    const int seqB = bj + 1;                 // sequence this block owns (1..60)
    const int t    = threadIdx.x;
    const int lane = t & 63;
    const int wv   = t >> 6;                 // wave 0..7
    const int kg   = lane >> 4;              // k-group 0..3
    const int col  = lane & 15;              // B/D column for this lane
    const int ur   = wv * 16;                // wave's unit base
    const int ub   = ur + kg * 4;            // this lane's 4-unit base

    // ---- gather x rows for BOTH sequences (deepest-latency loads first) ----
    for (int i = t; i < 2 * L_SZ * 32; i += TPB) {
        const int r  = i >> 5;               // 0..19
        const int e4 = i & 31;
        const int g  = (r < L_SZ) ? 0 : 1;
        const int l  = (r < L_SZ) ? r : r - L_SZ;
        int idx; const float* emb;
        if (g == 0)             { idx = phr_inds[l];                       emb = u_emb; }
        else if (seqB <= P_SZ)  { idx = pos_inds[(seqB - 1) * L_SZ + l];   emb = v_emb; }
        else                    { idx = neg_inds[(seqB - 1 - P_SZ) * L_SZ + l]; emb = v_emb; }
        const float4 v = *reinterpret_cast<const float4*>(emb + (size_t)idx * E_SZ + e4 * 4);
        short4 s4;
        s4.x = (short)f2bf(v.x); s4.y = (short)f2bf(v.y);
        s4.z = (short)f2bf(v.z); s4.w = (short)f2bf(v.w);
        *reinterpret_cast<short4*>((char*)&xs_bf16[g][0] + l * (XS_STR * 2) + e4 * 8) = s4;
    }
    // (B cols 10..15 uninitialized: their gi D-columns are never read)

    // ---- biases + h0 as f32x4 (every lane loads its 4-unit slice) ----
    const f32x4 bihr = *reinterpret_cast<const f32x4*>(b_ih + ub);
    const f32x4 bihz = *reinterpret_cast<const f32x4*>(b_ih + 128 + ub);
    const f32x4 bihn = *reinterpret_cast<const f32x4*>(b_ih + 256 + ub);
    const f32x4 bhhr = *reinterpret_cast<const f32x4*>(b_hh + ub);
    const f32x4 bhhz = *reinterpret_cast<const f32x4*>(b_hh + 128 + ub);
    const f32x4 bhhn = *reinterpret_cast<const f32x4*>(b_hh + 256 + ub);
    f32x4 hreg = *reinterpret_cast<const f32x4*>(h0 + ub);

    if (col < 2) {                           // gate lanes init the h broadcast
        short4 s4;
        s4.x = (short)f2bf(hreg[0]); s4.y = (short)f2bf(hreg[1]);
        s4.z = (short)f2bf(hreg[2]); s4.w = (short)f2bf(hreg[3]);
        *reinterpret_cast<short4*>(&hs_bf16[0][col][ub]) = s4;
    }

    // ---- weights: 2 passes of coalesced global -> swizzled 96 KB slab -> frags ----
    bf16x8 aih[3][4], ahh[3][4];             // [gate][kb], 96 VGPRs total
    #pragma unroll
    for (int m = 0; m < 2; ++m) {
        const float* W = (m == 0) ? w_ih : w_hh;
        #pragma unroll 8
        for (int q = 0; q < (384 * E_SZ / 4) / TPB; ++q) {   // 24 iters
            const int fi = q * TPB + t;
            const int lr = fi >> 5;          // row 0..383
            const int e4 = fi & 31;
            const float4 v = *reinterpret_cast<const float4*>(W + (size_t)lr * E_SZ + e4 * 4);
            short4 s4;
            s4.x = (short)f2bf(v.x); s4.y = (short)f2bf(v.y);
            s4.z = (short)f2bf(v.z); s4.w = (short)f2bf(v.w);
            const int byte = (lr * 256 + e4 * 8) ^ ((lr & 7) << 4);   // G4 XOR-swizzle
            *reinterpret_cast<short4*>((char*)stage_u + byte) = s4;
        }
        __syncthreads();                     // slab complete (also covers xs/hs init)

        #pragma unroll
        for (int gate = 0; gate < 3; ++gate) {
            const int lr = gate * H_SZ + ur + col;   // A row: gate block + unit row
            #pragma unroll
            for (int kb = 0; kb < 4; ++kb) {
                const int byte = (lr * 256 + kb * 64 + kg * 16) ^ ((lr & 7) << 4);
                const bf16x8 f = *reinterpret_cast<const bf16x8*>((const char*)stage_u + byte);
                if (m == 0) aih[gate][kb] = f;
                else        ahh[gate][kb] = f;
            }
        }
        __syncthreads();                     // frag reads done before slab reuse
    }
    // (after last barrier, stage_u is free -> becomes gi_all)

    // ---- gi = W_ih @ X^T (+b_ih folded), 12 MFMA per seq-group per wave ----
    #pragma unroll
    for (int g = 0; g < 2; ++g) {
        f32x4 ar = {0.f,0.f,0.f,0.f}, az = {0.f,0.f,0.f,0.f}, an = {0.f,0.f,0.f,0.f};
        #pragma unroll
        for (int kb = 0; kb < 4; ++kb) {
            const bf16x8 xb = *reinterpret_cast<const bf16x8*>(
                (const char*)&xs_bf16[g][0] + col * (XS_STR * 2) + kb * 64 + kg * 16);
            ar = MFMA(aih[0][kb], xb, ar);
            az = MFMA(aih[1][kb], xb, az);
            an = MFMA(aih[2][kb], xb, an);
        }
        if (col < L_SZ) {                    // D col = step l; D rows = units ub..ub+3
            const int base = (g * L_SZ + col) * 3;
            *reinterpret_cast<f32x4*>(&gi_all[(base + 0) * GI_USTR + ub]) = ar + bihr;
            *reinterpret_cast<f32x4*>(&gi_all[(base + 1) * GI_USTR + ub]) = az + bihz;
            *reinterpret_cast<f32x4*>(&gi_all[(base + 2) * GI_USTR + ub]) = an + bihn;
        }
    }
    __syncthreads();                         // gi_all visible to gate lanes

    // ---- recurrent steps: 12 MFMA/wave, in-register gates, 1 barrier/step ----
    int p = 0;
    for (int l = 0; l < L_SZ; ++l) {
        f32x4 ar = {0.f,0.f,0.f,0.f}, az = {0.f,0.f,0.f,0.f}, an = {0.f,0.f,0.f,0.f};
        #pragma unroll
        for (int kb = 0; kb < 4; ++kb) {
            // col parity selects which sequence's h this column multiplies
            const bf16x8 bh = *reinterpret_cast<const bf16x8*>(
                (const char*)&hs_bf16[p][col & 1][0] + kb * 64 + kg * 16);
            ar = MFMA(ahh[0][kb], bh, ar);
            az = MFMA(ahh[1][kb], bh, az);
            an = MFMA(ahh[2][kb], bh, an);
        }
        if (col < 2) {                       // this lane owns units ub..ub+3, seq=col
            const int base = (col * L_SZ + l) * 3;
            const f32x4 gr = *reinterpret_cast<const f32x4*>(&gi_all[(base + 0) * GI_USTR + ub]);
            const f32x4 gz = *reinterpret_cast<const f32x4*>(&gi_all[(base + 1) * GI_USTR + ub]);
            const f32x4 gn = *reinterpret_cast<const f32x4*>(&gi_all[(base + 2) * GI_USTR + ub]);
            #pragma unroll
            for (int j = 0; j < 4; ++j) {
                const float r = sigmoidf(gr[j] + (ar[j] + bhhr[j]));
                const float z = sigmoidf(gz[j] + (az[j] + bhhz[j]));
                const float n = tanhf  (gn[j] + r * (an[j] + bhhn[j]));
                hreg[j] = (1.0f - z) * n + z * hreg[j];
            }
            if (l < L_SZ - 1) {
                short4 s4;
                s4.x = (short)f2bf(hreg[0]); s4.y = (short)f2bf(hreg[1]);
                s4.z = (short)f2bf(hreg[2]); s4.w = (short)f2bf(hreg[3]);
                *reinterpret_cast<short4*>(&hs_bf16[p ^ 1][col][ub]) = s4;
            } else {
                *reinterpret_cast<f32x4*>(&node[col][ub]) = hreg;
            }
        }
        __syncthreads();                     // next-step h (or node) visible
        p ^= 1;
    }

    // ---- local dot: s = (node0 . node1) / 128, computed by wave 0 ----
    if (t >= 64) return;                     // no further barriers below

    float d = node[0][t] * node[1][t] + node[0][t + 64] * node[1][t + 64];
    #pragma unroll
    for (int off = 32; off > 0; off >>= 1) d += __shfl_down(d, off);
    const float s_own = d * (1.0f / (float)H_SZ);   // valid in lane 0

    // ---- publish (blocks 1..59) / aggregate (block 0) ----
    if (bj != 0) {
        if (t == 0) {
            slots[bj * SLOT_STRIDE] = s_own;   // plain store, bit-deterministic
            __threadfence();                   // release: slot visible before flag
            atomicExch(&flags[bj * FLAG_STRIDE], FLAG_MAGIC + (unsigned)bj);
        }
        return;
    }

    // block 0: lane 0 = own s; lanes 1..59 = block k's scalar.
    float sv = 0.0f;
    if (t == 0) sv = s_own;
    else if (t < NSEQ) {
        const unsigned want = FLAG_MAGIC + (unsigned)t;
        while (atomicAdd(&flags[t * FLAG_STRIDE], 0u) != want) {
            __builtin_amdgcn_s_sleep(2);
        }
        __threadfence();                       // acquire: order slot read after flag
        sv = slots[t * SLOT_STRIDE];
    }

    float vp = 0.0f, vn = 0.0f;
    if (t < P_SZ)      vp = sv;                              // rows 1..10: pos
    else if (t < NSEQ) vn = (sv > 0.0f) ? expf(sv) : 0.0f;   // rows 11..60: neg

    #pragma unroll
    for (int off = 32; off > 0; off >>= 1) {
        vp += __shfl_down(vp, off);
        vn += __shfl_down(vn, off);
    }
    if (t == 0) {
        out[0] = logf(1.0f + vn) - vp;   // -(neg_loss + pos_loss)
    }
}

extern "C" void kernel_launch(void* const* d_in, const int* in_sizes, int n_in,
                              void* d_out, int out_size, void* d_ws, size_t ws_size,
                              hipStream_t stream) {
    const int*   phr_inds = (const int*)  d_in[0];
    const int*   pos_inds = (const int*)  d_in[1];
    const int*   neg_inds = (const int*)  d_in[2];
    const float* u_emb    = (const float*)d_in[3];
    const float* v_emb    = (const float*)d_in[4];
    const float* w_ih     = (const float*)d_in[5];
    const float* w_hh     = (const float*)d_in[6];
    const float* b_ih     = (const float*)d_in[7];
    const float* b_hh     = (const float*)d_in[8];
    const float* h0       = (const float*)d_in[9];

    float*    slots = (float*)d_ws;                       // s scalars (strided)
    unsigned* flags = (unsigned*)((char*)d_ws + 16384);   // separate region

    gru_fused<<<NBLK, TPB, 0, stream>>>(phr_inds, pos_inds, neg_inds,
                                        u_emb, v_emb, w_ih, w_hh, b_ih, b_hh, h0,
                                        slots, flags, (float*)d_out);
}

// Round 15
// 21.995 us; speedup vs baseline: 1.4792x; 1.4792x over previous
//
#include <hip/hip_runtime.h>
#include <hip/hip_bf16.h>
#include <math.h>

// Problem constants (from reference)
#define V_SZ 500000
#define E_SZ 128
#define H_SZ 128
#define L_SZ 10
#define P_SZ 10
#define N_SZ 50
#define NSEQ (P_SZ + N_SZ)       // 60 non-phrase sequences
#define NBLK 60                  // block j handles (seq 0, seq j+1)
#define TPB  384                 // 6 waves; wave w owns gate rows [64w, 64w+64)

#define FLAG_STRIDE 16
#define SLOT_STRIDE 16
#define FLAG_MAGIC  0x9E370000u

#define GI_STR 388               // gi_all row stride (floats): 16B-aligned, ~2-way banks
#define XS_STR 136               // xs_bf16 row stride (bf16): 272B, 16B-aligned

typedef __attribute__((ext_vector_type(8))) short bf16x8;  // 8 bf16 = 4 VGPRs (MFMA A/B frag)
typedef __attribute__((ext_vector_type(4))) float f32x4;   // MFMA C/D frag

#define MFMA(a, b, c) __builtin_amdgcn_mfma_f32_16x16x32_bf16((a), (b), (c), 0, 0, 0)

__device__ __forceinline__ float sigmoidf(float x) {
    return 1.0f / (1.0f + expf(-x));
}

__device__ __forceinline__ unsigned short f2bf(float f) {   // RNE f32 -> bf16
    unsigned u = __float_as_uint(f);
    u += 0x7FFFu + ((u >> 16) & 1u);
    return (unsigned short)(u >> 16);
}

// R13 structure (proven 23.2 us) + ONE change: weight staging uses a single
// 96 KB slab (full 384-row matrix per pass, time-union'd with gi_all) ->
// 2 passes / 4 barriers instead of 4 passes / 8 barriers, and ALL 6 waves
// read fragments concurrently (R13: only 3 of 6 per pass).
// R14 lesson: do NOT repartition gates across waves (12.5%-exec nonlinearity
// chain + VGPR pressure regressed 9 us). Keep R13's t<256 gate phase.
__global__ __launch_bounds__(TPB) void gru_fused(
    const int*   __restrict__ phr_inds,
    const int*   __restrict__ pos_inds,
    const int*   __restrict__ neg_inds,
    const float* __restrict__ u_emb,
    const float* __restrict__ v_emb,
    const float* __restrict__ w_ih,
    const float* __restrict__ w_hh,
    const float* __restrict__ b_ih,
    const float* __restrict__ b_hh,
    const float* __restrict__ h0,
    float*       __restrict__ slots,    // [NBLK*SLOT_STRIDE] workspace (s scalars)
    unsigned*    __restrict__ flags,    // [NBLK*FLAG_STRIDE] workspace
    float*       __restrict__ out)      // f32 scalar
{
    // 96 KB: full weight matrix (384 rows x 128 bf16, XOR-swizzled) during
    // staging; re-used as gi_all (49.7 KB f32) afterwards (disjoint in time).
    __shared__ __align__(16) unsigned short stage_u[384 * E_SZ];      // 96 KB
    __shared__ __align__(16) unsigned short xs_bf16[2][16 * XS_STR];  // x^T per seq-group
    __shared__ __align__(16) float          gh_s[2][3 * H_SZ];        // gh exchange per seq
    __shared__ __align__(16) unsigned short hs_bf16[2][H_SZ];         // h broadcast per seq
    __shared__ __align__(16) float          node[2][H_SZ];            // final h (f32) per seq

    float* gi_all = (float*)stage_u;    // [2][16*GI_STR] alias; valid after staging

    const int bj   = blockIdx.x;             // 0..59
    const int seqB = bj + 1;                 // sequence this block owns (1..60)
    const int t    = threadIdx.x;
    const int lane = t & 63;
    const int wv   = t >> 6;                 // wave 0..5
    const int kg   = lane >> 4;              // k-group 0..3
    const int col  = lane & 15;              // B/D column for this lane
    const int arow = wv * 64 + col;          // A row (lane&15 = row within 16-block)

    // ---- gather x rows for BOTH sequences (deepest-latency loads first) ----
    for (int i = t; i < 2 * L_SZ * 32; i += TPB) {
        const int r  = i >> 5;               // 0..19
        const int e4 = i & 31;
        const int g  = (r < L_SZ) ? 0 : 1;
        const int l  = (r < L_SZ) ? r : r - L_SZ;
        int idx; const float* emb;
        if (g == 0)             { idx = phr_inds[l];                       emb = u_emb; }
        else if (seqB <= P_SZ)  { idx = pos_inds[(seqB - 1) * L_SZ + l];   emb = v_emb; }
        else                    { idx = neg_inds[(seqB - 1 - P_SZ) * L_SZ + l]; emb = v_emb; }
        const float4 v = *reinterpret_cast<const float4*>(emb + (size_t)idx * E_SZ + e4 * 4);
        short4 s4;
        s4.x = (short)f2bf(v.x); s4.y = (short)f2bf(v.y);
        s4.z = (short)f2bf(v.z); s4.w = (short)f2bf(v.w);
        *reinterpret_cast<short4*>((char*)&xs_bf16[g][0] + l * (XS_STR * 2) + e4 * 8) = s4;
    }
    // (cols 10..15 of each group left uninitialized: their gi outputs are never read)

    // ---- biases + h0 early (latency overlap; writes read only after barriers) ----
    const int gseq = t >> 7;                 // 0 or 1 (for t<256)
    const int gu   = t & 127;
    float bih_r = 0.f, bih_z = 0.f, bih_n = 0.f;
    float bhh_r = 0.f, bhh_z = 0.f, bhh_n = 0.f;
    float h_reg = 0.f;
    if (t < 2 * H_SZ) {
        bih_r = b_ih[gu]; bih_z = b_ih[gu + 128]; bih_n = b_ih[gu + 256];
        bhh_r = b_hh[gu]; bhh_z = b_hh[gu + 128]; bhh_n = b_hh[gu + 256];
        h_reg = h0[gu];
        hs_bf16[gseq][gu] = f2bf(h_reg);     // both groups init to h0
    }

    // ---- weights: 2 passes, full matrix per pass, all waves read frags ----
    bf16x8 aih[4][4], ahh[4][4];             // 128 VGPRs (R13-proven budget)
    #pragma unroll
    for (int m = 0; m < 2; ++m) {
        const float* W = (m == 0) ? w_ih : w_hh;
        // 384 rows x 128 f32, fully coalesced: 12288 float4 / 384 thr = 32 iters
        #pragma unroll 8
        for (int q = 0; q < (384 * E_SZ / 4) / TPB; ++q) {
            const int fi = q * TPB + t;
            const int lr = fi >> 5;          // row 0..383
            const int e4 = fi & 31;
            const float4 v = *reinterpret_cast<const float4*>(W + (size_t)lr * E_SZ + e4 * 4);
            short4 s4;
            s4.x = (short)f2bf(v.x); s4.y = (short)f2bf(v.y);
            s4.z = (short)f2bf(v.z); s4.w = (short)f2bf(v.w);
            const int byte = (lr * 256 + e4 * 8) ^ ((lr & 7) << 4);   // G4 XOR-swizzle
            *reinterpret_cast<short4*>((char*)stage_u + byte) = s4;
        }
        __syncthreads();                     // slab complete (also covers xs/hs init)

        #pragma unroll
        for (int mb = 0; mb < 4; ++mb) {
            const int lr = arow + mb * 16;   // this wave's A row (0..383)
            #pragma unroll
            for (int kb = 0; kb < 4; ++kb) {
                const int byte = (lr * 256 + kb * 64 + kg * 16) ^ ((lr & 7) << 4);
                const bf16x8 f = *reinterpret_cast<const bf16x8*>((const char*)stage_u + byte);
                if (m == 0) aih[mb][kb] = f;
                else        ahh[mb][kb] = f;
            }
        }
        __syncthreads();                     // frag reads done before slab reuse
    }
    // (after last barrier, stage_u is free -> becomes gi_all)

    // ---- gi = W_ih @ X^T, one MFMA pass per sequence group ----
    #pragma unroll
    for (int g = 0; g < 2; ++g) {
        f32x4 g0 = {0.f,0.f,0.f,0.f}, g1 = {0.f,0.f,0.f,0.f};
        f32x4 g2 = {0.f,0.f,0.f,0.f}, g3 = {0.f,0.f,0.f,0.f};
        #pragma unroll
        for (int kb = 0; kb < 4; ++kb) {
            const bf16x8 xb = *reinterpret_cast<const bf16x8*>(
                (const char*)&xs_bf16[g][0] + col * (XS_STR * 2) + kb * 64 + kg * 16);
            g0 = MFMA(aih[0][kb], xb, g0);
            g1 = MFMA(aih[1][kb], xb, g1);
            g2 = MFMA(aih[2][kb], xb, g2);
            g3 = MFMA(aih[3][kb], xb, g3);
        }
        const int rb = wv * 64 + kg * 4;     // D row base: (lane>>4)*4 + reg (m89-verified)
        *reinterpret_cast<f32x4*>(&gi_all[g * (16 * GI_STR) + col * GI_STR + rb     ]) = g0;
        *reinterpret_cast<f32x4*>(&gi_all[g * (16 * GI_STR) + col * GI_STR + rb + 16]) = g1;
        *reinterpret_cast<f32x4*>(&gi_all[g * (16 * GI_STR) + col * GI_STR + rb + 32]) = g2;
        *reinterpret_cast<f32x4*>(&gi_all[g * (16 * GI_STR) + col * GI_STR + rb + 48]) = g3;
    }
    // no barrier needed: step-0 barrier [A] orders gi_all writes before gate reads

    // ---- recurrent steps: 16 MFMA/wave/step, cols alternate seq0/seqB ----
    for (int l = 0; l < L_SZ; ++l) {
        f32x4 a0 = {0.f,0.f,0.f,0.f}, a1 = {0.f,0.f,0.f,0.f};
        f32x4 a2 = {0.f,0.f,0.f,0.f}, a3 = {0.f,0.f,0.f,0.f};
        #pragma unroll
        for (int kb = 0; kb < 4; ++kb) {
            // col parity selects which sequence's h this column multiplies
            const bf16x8 bh = *reinterpret_cast<const bf16x8*>(
                (const char*)&hs_bf16[col & 1][0] + kb * 64 + kg * 16);
            a0 = MFMA(ahh[0][kb], bh, a0);
            a1 = MFMA(ahh[1][kb], bh, a1);
            a2 = MFMA(ahh[2][kb], bh, a2);
            a3 = MFMA(ahh[3][kb], bh, a3);
        }
        if (col < 2) {                        // cols 0,1 hold gh for seq0 / seqB
            const int rb = wv * 64 + kg * 4;
            *reinterpret_cast<f32x4*>(&gh_s[col][rb     ]) = a0;
            *reinterpret_cast<f32x4*>(&gh_s[col][rb + 16]) = a1;
            *reinterpret_cast<f32x4*>(&gh_s[col][rb + 32]) = a2;
            *reinterpret_cast<f32x4*>(&gh_s[col][rb + 48]) = a3;
        }
        __syncthreads();                      // [A] gh_s (and, at l==0, gi_all) visible

        if (t < 2 * H_SZ) {
            const float* gi = &gi_all[gseq * (16 * GI_STR) + l * GI_STR];
            const float* gh = &gh_s[gseq][0];
            const float r = sigmoidf(gi[gu      ] + bih_r + (gh[gu      ] + bhh_r));
            const float z = sigmoidf(gi[gu + 128] + bih_z + (gh[gu + 128] + bhh_z));
            const float n = tanhf  (gi[gu + 256] + bih_n + r * (gh[gu + 256] + bhh_n));
            h_reg = (1.0f - z) * n + z * h_reg;
            if (l < L_SZ - 1) hs_bf16[gseq][gu] = f2bf(h_reg);  // re-broadcast
            else              node[gseq][gu]   = h_reg;         // final h (f32)
        }
        __syncthreads();                      // [B] hs_bf16 / node visible
    }

    // ---- local dot: s = (node0 . node1) / 128, computed by wave 0 ----
    if (t >= 64) return;                      // no further barriers below

    float d = node[0][t] * node[1][t] + node[0][t + 64] * node[1][t + 64];
    #pragma unroll
    for (int off = 32; off > 0; off >>= 1) d += __shfl_down(d, off);
    const float s_own = d * (1.0f / (float)H_SZ);   // valid in lane 0

    // ---- publish (blocks 1..59) / aggregate (block 0) ----
    if (bj != 0) {
        if (t == 0) {
            slots[bj * SLOT_STRIDE] = s_own;   // plain store, bit-deterministic
            __threadfence();                   // release: slot visible before flag
            atomicExch(&flags[bj * FLAG_STRIDE], FLAG_MAGIC + (unsigned)bj);
        }
        return;
    }

    // block 0: lane 0 = own s; lanes 1..59 = block k's scalar.
    float sv = 0.0f;
    if (t == 0) sv = s_own;
    else if (t < NSEQ) {
        const unsigned want = FLAG_MAGIC + (unsigned)t;
        while (atomicAdd(&flags[t * FLAG_STRIDE], 0u) != want) {
            __builtin_amdgcn_s_sleep(2);
        }
        __threadfence();                       // acquire: order slot read after flag
        sv = slots[t * SLOT_STRIDE];
    }

    float vp = 0.0f, vn = 0.0f;
    if (t < P_SZ)      vp = sv;                              // rows 1..10: pos
    else if (t < NSEQ) vn = (sv > 0.0f) ? expf(sv) : 0.0f;   // rows 11..60: neg

    #pragma unroll
    for (int off = 32; off > 0; off >>= 1) {
        vp += __shfl_down(vp, off);
        vn += __shfl_down(vn, off);
    }
    if (t == 0) {
        out[0] = logf(1.0f + vn) - vp;   // -(neg_loss + pos_loss)
    }
}

extern "C" void kernel_launch(void* const* d_in, const int* in_sizes, int n_in,
                              void* d_out, int out_size, void* d_ws, size_t ws_size,
                              hipStream_t stream) {
    const int*   phr_inds = (const int*)  d_in[0];
    const int*   pos_inds = (const int*)  d_in[1];
    const int*   neg_inds = (const int*)  d_in[2];
    const float* u_emb    = (const float*)d_in[3];
    const float* v_emb    = (const float*)d_in[4];
    const float* w_ih     = (const float*)d_in[5];
    const float* w_hh     = (const float*)d_in[6];
    const float* b_ih     = (const float*)d_in[7];
    const float* b_hh     = (const float*)d_in[8];
    const float* h0       = (const float*)d_in[9];

    float*    slots = (float*)d_ws;                       // s scalars (strided)
    unsigned* flags = (unsigned*)((char*)d_ws + 16384);   // separate region

    gru_fused<<<NBLK, TPB, 0, stream>>>(phr_inds, pos_inds, neg_inds,
                                        u_emb, v_emb, w_ih, w_hh, b_ih, b_hh, h0,
                                        slots, flags, (float*)d_out);
}

// Round 16
// 21.093 us; speedup vs baseline: 1.5424x; 1.0428x over previous
//
#include <hip/hip_runtime.h>
#include <hip/hip_bf16.h>
#include <math.h>

// Problem constants (from reference)
#define V_SZ 500000
#define E_SZ 128
#define H_SZ 128
#define L_SZ 10
#define P_SZ 10
#define N_SZ 50
#define NSEQ (P_SZ + N_SZ)       // 60 non-phrase sequences
#define NBLK 60                  // block j handles (seq 0, seq j+1)
#define TPB  384                 // 6 waves; wave w owns gate rows [64w, 64w+64)

#define FLAG_STRIDE 16
#define SLOT_STRIDE 16
#define FLAG_MAGIC  0x9E370000u

#define GI_STR 388               // gi_all row stride (floats): 16B-aligned, ~2-way banks
#define XS_STR 136               // xs_bf16 row stride (bf16): 272B, 16B-aligned

typedef __attribute__((ext_vector_type(8))) short bf16x8;  // 8 bf16 = 4 VGPRs (MFMA A/B frag)
typedef __attribute__((ext_vector_type(4))) float f32x4;   // MFMA C/D frag

#define MFMA(a, b, c) __builtin_amdgcn_mfma_f32_16x16x32_bf16((a), (b), (c), 0, 0, 0)

__device__ __forceinline__ float sigmoidf(float x) {
    return 1.0f / (1.0f + expf(-x));
}

// RNE f32->bf16 via HW converter (v_cvt_pk_bf16_f32) — same rounding as the
// old manual bit-math, ~8x fewer VALU ops (R16 change).
__device__ __forceinline__ unsigned short f2bf(float f) {
    __hip_bfloat16 h = __float2bfloat16(f);
    unsigned short u;
    __builtin_memcpy(&u, &h, sizeof(u));
    return u;
}

__device__ __forceinline__ unsigned f2bf2(float lo, float hi) {   // packed 2xbf16
    float2 v = make_float2(lo, hi);
    __hip_bfloat162 h2 = __float22bfloat162_rn(v);
    unsigned u;
    __builtin_memcpy(&u, &h2, sizeof(u));
    return u;
}

__device__ __forceinline__ uint2 f2bf4(float4 v) {                // packed 4xbf16
    uint2 r;
    r.x = f2bf2(v.x, v.y);
    r.y = f2bf2(v.z, v.w);
    return r;
}

// R15 structure (proven 22.0 us): 96 KB weight slab (2 passes, union'd with
// gi_all), dual-sequence columns, scalar handshake. R16: all f32->bf16
// conversion through the HW pair-converter.
__global__ __launch_bounds__(TPB) void gru_fused(
    const int*   __restrict__ phr_inds,
    const int*   __restrict__ pos_inds,
    const int*   __restrict__ neg_inds,
    const float* __restrict__ u_emb,
    const float* __restrict__ v_emb,
    const float* __restrict__ w_ih,
    const float* __restrict__ w_hh,
    const float* __restrict__ b_ih,
    const float* __restrict__ b_hh,
    const float* __restrict__ h0,
    float*       __restrict__ slots,    // [NBLK*SLOT_STRIDE] workspace (s scalars)
    unsigned*    __restrict__ flags,    // [NBLK*FLAG_STRIDE] workspace
    float*       __restrict__ out)      // f32 scalar
{
    // 96 KB: full weight matrix (384 rows x 128 bf16, XOR-swizzled) during
    // staging; re-used as gi_all (49.7 KB f32) afterwards (disjoint in time).
    __shared__ __align__(16) unsigned short stage_u[384 * E_SZ];      // 96 KB
    __shared__ __align__(16) unsigned short xs_bf16[2][16 * XS_STR];  // x^T per seq-group
    __shared__ __align__(16) float          gh_s[2][3 * H_SZ];        // gh exchange per seq
    __shared__ __align__(16) unsigned short hs_bf16[2][H_SZ];         // h broadcast per seq
    __shared__ __align__(16) float          node[2][H_SZ];            // final h (f32) per seq

    float* gi_all = (float*)stage_u;    // [2][16*GI_STR] alias; valid after staging

    const int bj   = blockIdx.x;             // 0..59
    const int seqB = bj + 1;                 // sequence this block owns (1..60)
    const int t    = threadIdx.x;
    const int lane = t & 63;
    const int wv   = t >> 6;                 // wave 0..5
    const int kg   = lane >> 4;              // k-group 0..3
    const int col  = lane & 15;              // B/D column for this lane
    const int arow = wv * 64 + col;          // A row (lane&15 = row within 16-block)

    // ---- gather x rows for BOTH sequences (deepest-latency loads first) ----
    for (int i = t; i < 2 * L_SZ * 32; i += TPB) {
        const int r  = i >> 5;               // 0..19
        const int e4 = i & 31;
        const int g  = (r < L_SZ) ? 0 : 1;
        const int l  = (r < L_SZ) ? r : r - L_SZ;
        int idx; const float* emb;
        if (g == 0)             { idx = phr_inds[l];                       emb = u_emb; }
        else if (seqB <= P_SZ)  { idx = pos_inds[(seqB - 1) * L_SZ + l];   emb = v_emb; }
        else                    { idx = neg_inds[(seqB - 1 - P_SZ) * L_SZ + l]; emb = v_emb; }
        const float4 v = *reinterpret_cast<const float4*>(emb + (size_t)idx * E_SZ + e4 * 4);
        *reinterpret_cast<uint2*>((char*)&xs_bf16[g][0] + l * (XS_STR * 2) + e4 * 8) = f2bf4(v);
    }
    // (cols 10..15 of each group left uninitialized: their gi outputs are never read)

    // ---- biases + h0 early (latency overlap; writes read only after barriers) ----
    const int gseq = t >> 7;                 // 0 or 1 (for t<256)
    const int gu   = t & 127;
    float bih_r = 0.f, bih_z = 0.f, bih_n = 0.f;
    float bhh_r = 0.f, bhh_z = 0.f, bhh_n = 0.f;
    float h_reg = 0.f;
    if (t < 2 * H_SZ) {
        bih_r = b_ih[gu]; bih_z = b_ih[gu + 128]; bih_n = b_ih[gu + 256];
        bhh_r = b_hh[gu]; bhh_z = b_hh[gu + 128]; bhh_n = b_hh[gu + 256];
        h_reg = h0[gu];
        hs_bf16[gseq][gu] = f2bf(h_reg);     // both groups init to h0
    }

    // ---- weights: 2 passes, full matrix per pass, all waves read frags ----
    bf16x8 aih[4][4], ahh[4][4];             // 128 VGPRs (R13-proven budget)
    #pragma unroll
    for (int m = 0; m < 2; ++m) {
        const float* W = (m == 0) ? w_ih : w_hh;
        // 384 rows x 128 f32, fully coalesced: 12288 float4 / 384 thr = 32 iters
        #pragma unroll 8
        for (int q = 0; q < (384 * E_SZ / 4) / TPB; ++q) {
            const int fi = q * TPB + t;
            const int lr = fi >> 5;          // row 0..383
            const int e4 = fi & 31;
            const float4 v = *reinterpret_cast<const float4*>(W + (size_t)lr * E_SZ + e4 * 4);
            const int byte = (lr * 256 + e4 * 8) ^ ((lr & 7) << 4);   // G4 XOR-swizzle
            *reinterpret_cast<uint2*>((char*)stage_u + byte) = f2bf4(v);
        }
        __syncthreads();                     // slab complete (also covers xs/hs init)

        #pragma unroll
        for (int mb = 0; mb < 4; ++mb) {
            const int lr = arow + mb * 16;   // this wave's A row (0..383)
            #pragma unroll
            for (int kb = 0; kb < 4; ++kb) {
                const int byte = (lr * 256 + kb * 64 + kg * 16) ^ ((lr & 7) << 4);
                const bf16x8 f = *reinterpret_cast<const bf16x8*>((const char*)stage_u + byte);
                if (m == 0) aih[mb][kb] = f;
                else        ahh[mb][kb] = f;
            }
        }
        __syncthreads();                     // frag reads done before slab reuse
    }
    // (after last barrier, stage_u is free -> becomes gi_all)

    // ---- gi = W_ih @ X^T, one MFMA pass per sequence group ----
    #pragma unroll
    for (int g = 0; g < 2; ++g) {
        f32x4 g0 = {0.f,0.f,0.f,0.f}, g1 = {0.f,0.f,0.f,0.f};
        f32x4 g2 = {0.f,0.f,0.f,0.f}, g3 = {0.f,0.f,0.f,0.f};
        #pragma unroll
        for (int kb = 0; kb < 4; ++kb) {
            const bf16x8 xb = *reinterpret_cast<const bf16x8*>(
                (const char*)&xs_bf16[g][0] + col * (XS_STR * 2) + kb * 64 + kg * 16);
            g0 = MFMA(aih[0][kb], xb, g0);
            g1 = MFMA(aih[1][kb], xb, g1);
            g2 = MFMA(aih[2][kb], xb, g2);
            g3 = MFMA(aih[3][kb], xb, g3);
        }
        const int rb = wv * 64 + kg * 4;     // D row base: (lane>>4)*4 + reg (m89-verified)
        *reinterpret_cast<f32x4*>(&gi_all[g * (16 * GI_STR) + col * GI_STR + rb     ]) = g0;
        *reinterpret_cast<f32x4*>(&gi_all[g * (16 * GI_STR) + col * GI_STR + rb + 16]) = g1;
        *reinterpret_cast<f32x4*>(&gi_all[g * (16 * GI_STR) + col * GI_STR + rb + 32]) = g2;
        *reinterpret_cast<f32x4*>(&gi_all[g * (16 * GI_STR) + col * GI_STR + rb + 48]) = g3;
    }
    // no barrier needed: step-0 barrier [A] orders gi_all writes before gate reads

    // ---- recurrent steps: 16 MFMA/wave/step, cols alternate seq0/seqB ----
    for (int l = 0; l < L_SZ; ++l) {
        f32x4 a0 = {0.f,0.f,0.f,0.f}, a1 = {0.f,0.f,0.f,0.f};
        f32x4 a2 = {0.f,0.f,0.f,0.f}, a3 = {0.f,0.f,0.f,0.f};
        #pragma unroll
        for (int kb = 0; kb < 4; ++kb) {
            // col parity selects which sequence's h this column multiplies
            const bf16x8 bh = *reinterpret_cast<const bf16x8*>(
                (const char*)&hs_bf16[col & 1][0] + kb * 64 + kg * 16);
            a0 = MFMA(ahh[0][kb], bh, a0);
            a1 = MFMA(ahh[1][kb], bh, a1);
            a2 = MFMA(ahh[2][kb], bh, a2);
            a3 = MFMA(ahh[3][kb], bh, a3);
        }
        if (col < 2) {                        // cols 0,1 hold gh for seq0 / seqB
            const int rb = wv * 64 + kg * 4;
            *reinterpret_cast<f32x4*>(&gh_s[col][rb     ]) = a0;
            *reinterpret_cast<f32x4*>(&gh_s[col][rb + 16]) = a1;
            *reinterpret_cast<f32x4*>(&gh_s[col][rb + 32]) = a2;
            *reinterpret_cast<f32x4*>(&gh_s[col][rb + 48]) = a3;
        }
        __syncthreads();                      // [A] gh_s (and, at l==0, gi_all) visible

        if (t < 2 * H_SZ) {
            const float* gi = &gi_all[gseq * (16 * GI_STR) + l * GI_STR];
            const float* gh = &gh_s[gseq][0];
            const float r = sigmoidf(gi[gu      ] + bih_r + (gh[gu      ] + bhh_r));
            const float z = sigmoidf(gi[gu + 128] + bih_z + (gh[gu + 128] + bhh_z));
            const float n = tanhf  (gi[gu + 256] + bih_n + r * (gh[gu + 256] + bhh_n));
            h_reg = (1.0f - z) * n + z * h_reg;
            if (l < L_SZ - 1) hs_bf16[gseq][gu] = f2bf(h_reg);  // re-broadcast
            else              node[gseq][gu]   = h_reg;         // final h (f32)
        }
        __syncthreads();                      // [B] hs_bf16 / node visible
    }

    // ---- local dot: s = (node0 . node1) / 128, computed by wave 0 ----
    if (t >= 64) return;                      // no further barriers below

    float d = node[0][t] * node[1][t] + node[0][t + 64] * node[1][t + 64];
    #pragma unroll
    for (int off = 32; off > 0; off >>= 1) d += __shfl_down(d, off);
    const float s_own = d * (1.0f / (float)H_SZ);   // valid in lane 0

    // ---- publish (blocks 1..59) / aggregate (block 0) ----
    if (bj != 0) {
        if (t == 0) {
            slots[bj * SLOT_STRIDE] = s_own;   // plain store, bit-deterministic
            __threadfence();                   // release: slot visible before flag
            atomicExch(&flags[bj * FLAG_STRIDE], FLAG_MAGIC + (unsigned)bj);
        }
        return;
    }

    // block 0: lane 0 = own s; lanes 1..59 = block k's scalar.
    float sv = 0.0f;
    if (t == 0) sv = s_own;
    else if (t < NSEQ) {
        const unsigned want = FLAG_MAGIC + (unsigned)t;
        while (atomicAdd(&flags[t * FLAG_STRIDE], 0u) != want) {
            __builtin_amdgcn_s_sleep(2);
        }
        __threadfence();                       // acquire: order slot read after flag
        sv = slots[t * SLOT_STRIDE];
    }

    float vp = 0.0f, vn = 0.0f;
    if (t < P_SZ)      vp = sv;                              // rows 1..10: pos
    else if (t < NSEQ) vn = (sv > 0.0f) ? expf(sv) : 0.0f;   // rows 11..60: neg

    #pragma unroll
    for (int off = 32; off > 0; off >>= 1) {
        vp += __shfl_down(vp, off);
        vn += __shfl_down(vn, off);
    }
    if (t == 0) {
        out[0] = logf(1.0f + vn) - vp;   // -(neg_loss + pos_loss)
    }
}

extern "C" void kernel_launch(void* const* d_in, const int* in_sizes, int n_in,
                              void* d_out, int out_size, void* d_ws, size_t ws_size,
                              hipStream_t stream) {
    const int*   phr_inds = (const int*)  d_in[0];
    const int*   pos_inds = (const int*)  d_in[1];
    const int*   neg_inds = (const int*)  d_in[2];
    const float* u_emb    = (const float*)d_in[3];
    const float* v_emb    = (const float*)d_in[4];
    const float* w_ih     = (const float*)d_in[5];
    const float* w_hh     = (const float*)d_in[6];
    const float* b_ih     = (const float*)d_in[7];
    const float* b_hh     = (const float*)d_in[8];
    const float* h0       = (const float*)d_in[9];

    float*    slots = (float*)d_ws;                       // s scalars (strided)
    unsigned* flags = (unsigned*)((char*)d_ws + 16384);   // separate region

    gru_fused<<<NBLK, TPB, 0, stream>>>(phr_inds, pos_inds, neg_inds,
                                        u_emb, v_emb, w_ih, w_hh, b_ih, b_hh, h0,
                                        slots, flags, (float*)d_out);
}

// Round 17
// 20.479 us; speedup vs baseline: 1.5886x; 1.0300x over previous
//
#include <hip/hip_runtime.h>
#include <hip/hip_bf16.h>
#include <math.h>

// Problem constants (from reference)
#define V_SZ 500000
#define E_SZ 128
#define H_SZ 128
#define L_SZ 10
#define P_SZ 10
#define N_SZ 50
#define NSEQ (P_SZ + N_SZ)       // 60 non-phrase sequences
#define NBLK 60                  // block j handles (seq 0, seq j+1)
#define TPB  384                 // 6 waves; wave w owns gate rows [64w, 64w+64)

#define SIG_STRIDE 8             // 64 B between signal words (line separation)
#define FLAG_MAGIC 0x9E370000u

#define GI_STR 388               // gi_all row stride (floats): 16B-aligned, ~2-way banks
#define XS_STR 136               // xs_bf16 row stride (bf16): 272B, 16B-aligned

typedef __attribute__((ext_vector_type(8))) short bf16x8;  // 8 bf16 = 4 VGPRs (MFMA A/B frag)
typedef __attribute__((ext_vector_type(4))) float f32x4;   // MFMA C/D frag

#define MFMA(a, b, c) __builtin_amdgcn_mfma_f32_16x16x32_bf16((a), (b), (c), 0, 0, 0)

__device__ __forceinline__ float sigmoidf(float x) {
    return 1.0f / (1.0f + expf(-x));
}

// RNE f32->bf16 via HW converter (v_cvt_pk_bf16_f32) — R16-proven
__device__ __forceinline__ unsigned short f2bf(float f) {
    __hip_bfloat16 h = __float2bfloat16(f);
    unsigned short u;
    __builtin_memcpy(&u, &h, sizeof(u));
    return u;
}

__device__ __forceinline__ unsigned f2bf2(float lo, float hi) {   // packed 2xbf16
    float2 v = make_float2(lo, hi);
    __hip_bfloat162 h2 = __float22bfloat162_rn(v);
    unsigned u;
    __builtin_memcpy(&u, &h2, sizeof(u));
    return u;
}

__device__ __forceinline__ uint2 f2bf4(float4 v) {                // packed 4xbf16
    uint2 r;
    r.x = f2bf2(v.x, v.y);
    r.y = f2bf2(v.z, v.w);
    return r;
}

// R16 structure (proven 21.1 us). R17 change: the inter-block handshake packs
// {magic, f32 payload} into ONE 8-byte atomicExch — no fences, no dependent
// second read on the consumer side (tail was 2 serialized ~900cy round-trips).
__global__ __launch_bounds__(TPB) void gru_fused(
    const int*   __restrict__ phr_inds,
    const int*   __restrict__ pos_inds,
    const int*   __restrict__ neg_inds,
    const float* __restrict__ u_emb,
    const float* __restrict__ v_emb,
    const float* __restrict__ w_ih,
    const float* __restrict__ w_hh,
    const float* __restrict__ b_ih,
    const float* __restrict__ b_hh,
    const float* __restrict__ h0,
    unsigned long long* __restrict__ sig,   // [NBLK*SIG_STRIDE] workspace
    float*       __restrict__ out)          // f32 scalar
{
    // 96 KB: full weight matrix (384 rows x 128 bf16, XOR-swizzled) during
    // staging; re-used as gi_all (49.7 KB f32) afterwards (disjoint in time).
    __shared__ __align__(16) unsigned short stage_u[384 * E_SZ];      // 96 KB
    __shared__ __align__(16) unsigned short xs_bf16[2][16 * XS_STR];  // x^T per seq-group
    __shared__ __align__(16) float          gh_s[2][3 * H_SZ];        // gh exchange per seq
    __shared__ __align__(16) unsigned short hs_bf16[2][H_SZ];         // h broadcast per seq
    __shared__ __align__(16) float          node[2][H_SZ];            // final h (f32) per seq

    float* gi_all = (float*)stage_u;    // [2][16*GI_STR] alias; valid after staging

    const int bj   = blockIdx.x;             // 0..59
    const int seqB = bj + 1;                 // sequence this block owns (1..60)
    const int t    = threadIdx.x;
    const int lane = t & 63;
    const int wv   = t >> 6;                 // wave 0..5
    const int kg   = lane >> 4;              // k-group 0..3
    const int col  = lane & 15;              // B/D column for this lane
    const int arow = wv * 64 + col;          // A row (lane&15 = row within 16-block)

    // ---- gather x rows for BOTH sequences (deepest-latency loads first) ----
    for (int i = t; i < 2 * L_SZ * 32; i += TPB) {
        const int r  = i >> 5;               // 0..19
        const int e4 = i & 31;
        const int g  = (r < L_SZ) ? 0 : 1;
        const int l  = (r < L_SZ) ? r : r - L_SZ;
        int idx; const float* emb;
        if (g == 0)             { idx = phr_inds[l];                       emb = u_emb; }
        else if (seqB <= P_SZ)  { idx = pos_inds[(seqB - 1) * L_SZ + l];   emb = v_emb; }
        else                    { idx = neg_inds[(seqB - 1 - P_SZ) * L_SZ + l]; emb = v_emb; }
        const float4 v = *reinterpret_cast<const float4*>(emb + (size_t)idx * E_SZ + e4 * 4);
        *reinterpret_cast<uint2*>((char*)&xs_bf16[g][0] + l * (XS_STR * 2) + e4 * 8) = f2bf4(v);
    }
    // (cols 10..15 of each group left uninitialized: their gi outputs are never read)

    // ---- biases + h0 early (latency overlap; writes read only after barriers) ----
    const int gseq = t >> 7;                 // 0 or 1 (for t<256)
    const int gu   = t & 127;
    float bih_r = 0.f, bih_z = 0.f, bih_n = 0.f;
    float bhh_r = 0.f, bhh_z = 0.f, bhh_n = 0.f;
    float h_reg = 0.f;
    if (t < 2 * H_SZ) {
        bih_r = b_ih[gu]; bih_z = b_ih[gu + 128]; bih_n = b_ih[gu + 256];
        bhh_r = b_hh[gu]; bhh_z = b_hh[gu + 128]; bhh_n = b_hh[gu + 256];
        h_reg = h0[gu];
        hs_bf16[gseq][gu] = f2bf(h_reg);     // both groups init to h0
    }

    // ---- weights: 2 passes, full matrix per pass, all waves read frags ----
    bf16x8 aih[4][4], ahh[4][4];             // 128 VGPRs (R13-proven budget)
    #pragma unroll
    for (int m = 0; m < 2; ++m) {
        const float* W = (m == 0) ? w_ih : w_hh;
        // 384 rows x 128 f32, fully coalesced: 12288 float4 / 384 thr = 32 iters
        #pragma unroll 8
        for (int q = 0; q < (384 * E_SZ / 4) / TPB; ++q) {
            const int fi = q * TPB + t;
            const int lr = fi >> 5;          // row 0..383
            const int e4 = fi & 31;
            const float4 v = *reinterpret_cast<const float4*>(W + (size_t)lr * E_SZ + e4 * 4);
            const int byte = (lr * 256 + e4 * 8) ^ ((lr & 7) << 4);   // G4 XOR-swizzle
            *reinterpret_cast<uint2*>((char*)stage_u + byte) = f2bf4(v);
        }
        __syncthreads();                     // slab complete (also covers xs/hs init)

        #pragma unroll
        for (int mb = 0; mb < 4; ++mb) {
            const int lr = arow + mb * 16;   // this wave's A row (0..383)
            #pragma unroll
            for (int kb = 0; kb < 4; ++kb) {
                const int byte = (lr * 256 + kb * 64 + kg * 16) ^ ((lr & 7) << 4);
                const bf16x8 f = *reinterpret_cast<const bf16x8*>((const char*)stage_u + byte);
                if (m == 0) aih[mb][kb] = f;
                else        ahh[mb][kb] = f;
            }
        }
        __syncthreads();                     // frag reads done before slab reuse
    }
    // (after last barrier, stage_u is free -> becomes gi_all)

    // ---- gi = W_ih @ X^T, one MFMA pass per sequence group ----
    #pragma unroll
    for (int g = 0; g < 2; ++g) {
        f32x4 g0 = {0.f,0.f,0.f,0.f}, g1 = {0.f,0.f,0.f,0.f};
        f32x4 g2 = {0.f,0.f,0.f,0.f}, g3 = {0.f,0.f,0.f,0.f};
        #pragma unroll
        for (int kb = 0; kb < 4; ++kb) {
            const bf16x8 xb = *reinterpret_cast<const bf16x8*>(
                (const char*)&xs_bf16[g][0] + col * (XS_STR * 2) + kb * 64 + kg * 16);
            g0 = MFMA(aih[0][kb], xb, g0);
            g1 = MFMA(aih[1][kb], xb, g1);
            g2 = MFMA(aih[2][kb], xb, g2);
            g3 = MFMA(aih[3][kb], xb, g3);
        }
        const int rb = wv * 64 + kg * 4;     // D row base: (lane>>4)*4 + reg (m89-verified)
        *reinterpret_cast<f32x4*>(&gi_all[g * (16 * GI_STR) + col * GI_STR + rb     ]) = g0;
        *reinterpret_cast<f32x4*>(&gi_all[g * (16 * GI_STR) + col * GI_STR + rb + 16]) = g1;
        *reinterpret_cast<f32x4*>(&gi_all[g * (16 * GI_STR) + col * GI_STR + rb + 32]) = g2;
        *reinterpret_cast<f32x4*>(&gi_all[g * (16 * GI_STR) + col * GI_STR + rb + 48]) = g3;
    }
    // no barrier needed: step-0 barrier [A] orders gi_all writes before gate reads

    // ---- recurrent steps: 16 MFMA/wave/step, cols alternate seq0/seqB ----
    for (int l = 0; l < L_SZ; ++l) {
        f32x4 a0 = {0.f,0.f,0.f,0.f}, a1 = {0.f,0.f,0.f,0.f};
        f32x4 a2 = {0.f,0.f,0.f,0.f}, a3 = {0.f,0.f,0.f,0.f};
        #pragma unroll
        for (int kb = 0; kb < 4; ++kb) {
            // col parity selects which sequence's h this column multiplies
            const bf16x8 bh = *reinterpret_cast<const bf16x8*>(
                (const char*)&hs_bf16[col & 1][0] + kb * 64 + kg * 16);
            a0 = MFMA(ahh[0][kb], bh, a0);
            a1 = MFMA(ahh[1][kb], bh, a1);
            a2 = MFMA(ahh[2][kb], bh, a2);
            a3 = MFMA(ahh[3][kb], bh, a3);
        }
        if (col < 2) {                        // cols 0,1 hold gh for seq0 / seqB
            const int rb = wv * 64 + kg * 4;
            *reinterpret_cast<f32x4*>(&gh_s[col][rb     ]) = a0;
            *reinterpret_cast<f32x4*>(&gh_s[col][rb + 16]) = a1;
            *reinterpret_cast<f32x4*>(&gh_s[col][rb + 32]) = a2;
            *reinterpret_cast<f32x4*>(&gh_s[col][rb + 48]) = a3;
        }
        __syncthreads();                      // [A] gh_s (and, at l==0, gi_all) visible

        if (t < 2 * H_SZ) {
            const float* gi = &gi_all[gseq * (16 * GI_STR) + l * GI_STR];
            const float* gh = &gh_s[gseq][0];
            const float r = sigmoidf(gi[gu      ] + bih_r + (gh[gu      ] + bhh_r));
            const float z = sigmoidf(gi[gu + 128] + bih_z + (gh[gu + 128] + bhh_z));
            const float n = tanhf  (gi[gu + 256] + bih_n + r * (gh[gu + 256] + bhh_n));
            h_reg = (1.0f - z) * n + z * h_reg;
            if (l < L_SZ - 1) hs_bf16[gseq][gu] = f2bf(h_reg);  // re-broadcast
            else              node[gseq][gu]   = h_reg;         // final h (f32)
        }
        __syncthreads();                      // [B] hs_bf16 / node visible
    }

    // ---- local dot: s = (node0 . node1) / 128, computed by wave 0 ----
    if (t >= 64) return;                      // no further barriers below

    float d = node[0][t] * node[1][t] + node[0][t + 64] * node[1][t + 64];
    #pragma unroll
    for (int off = 32; off > 0; off >>= 1) d += __shfl_down(d, off);
    const float s_own = d * (1.0f / (float)H_SZ);   // valid in lane 0

    // ---- publish (blocks 1..59) / aggregate (block 0) ----
    // Payload rides INSIDE the 8-byte atomic: high32 = magic+id, low32 = f32
    // bits. No fences, no dependent second read (R17 change).
    if (bj != 0) {
        if (t == 0) {
            const unsigned long long v =
                ((unsigned long long)(FLAG_MAGIC + (unsigned)bj) << 32) |
                (unsigned long long)__float_as_uint(s_own);
            atomicExch(&sig[bj * SIG_STRIDE], v);   // device-scope, idempotent
        }
        return;
    }

    // block 0: lane 0 = own s; lanes 1..59 poll block k's packed signal.
    float sv = 0.0f;
    if (t == 0) sv = s_own;
    else if (t < NSEQ) {
        const unsigned want = FLAG_MAGIC + (unsigned)t;
        unsigned long long v;
        do {
            v = atomicAdd(&sig[t * SIG_STRIDE], 0ull);   // coherent 8-byte read
            if ((unsigned)(v >> 32) == want) break;
            __builtin_amdgcn_s_sleep(2);
        } while (true);
        sv = __uint_as_float((unsigned)(v & 0xFFFFFFFFull));
    }

    float vp = 0.0f, vn = 0.0f;
    if (t < P_SZ)      vp = sv;                              // rows 1..10: pos
    else if (t < NSEQ) vn = (sv > 0.0f) ? expf(sv) : 0.0f;   // rows 11..60: neg

    #pragma unroll
    for (int off = 32; off > 0; off >>= 1) {
        vp += __shfl_down(vp, off);
        vn += __shfl_down(vn, off);
    }
    if (t == 0) {
        out[0] = logf(1.0f + vn) - vp;   // -(neg_loss + pos_loss)
    }
}

extern "C" void kernel_launch(void* const* d_in, const int* in_sizes, int n_in,
                              void* d_out, int out_size, void* d_ws, size_t ws_size,
                              hipStream_t stream) {
    const int*   phr_inds = (const int*)  d_in[0];
    const int*   pos_inds = (const int*)  d_in[1];
    const int*   neg_inds = (const int*)  d_in[2];
    const float* u_emb    = (const float*)d_in[3];
    const float* v_emb    = (const float*)d_in[4];
    const float* w_ih     = (const float*)d_in[5];
    const float* w_hh     = (const float*)d_in[6];
    const float* b_ih     = (const float*)d_in[7];
    const float* b_hh     = (const float*)d_in[8];
    const float* h0       = (const float*)d_in[9];

    unsigned long long* sig = (unsigned long long*)d_ws;   // 60 x 64 B signals

    gru_fused<<<NBLK, TPB, 0, stream>>>(phr_inds, pos_inds, neg_inds,
                                        u_emb, v_emb, w_ih, w_hh, b_ih, b_hh, h0,
                                        sig, (float*)d_out);
}